// Round 5
// baseline (173.464 us; speedup 1.0000x reference)
//
#include <hip/hip_runtime.h>
#include <hip/hip_bf16.h>

typedef __attribute__((ext_vector_type(8))) short short8;
typedef __attribute__((ext_vector_type(4))) float f32x4;

// Problem constants (from reference)
constexpr int NN = 50000;   // nodes
constexpr int NE = 800000;  // edges
constexpr int FN = 64;      // node feat
constexpr int FE = 32;      // edge feat
constexpr int FG = 32;      // global feat
constexpr int OD = 64;      // out dim
constexpr int NG = 256;     // graphs

constexpr int SCAN_B = 256;
constexpr int NBLK = (NN + SCAN_B - 1) / SCAN_B;  // 196

constexpr int SLOTS_MAX = NE + 15 * NN;           // 1.55M padded bucket slots
constexpr int AGG_BLOCKS = 2048;                  // persistent, 8 blocks/CU
constexpr int AGG_WAVES  = AGG_BLOCKS * 4;
constexpr int NWIN       = NN / 16;               // 3125 node-windows (exact)
constexpr int NODE_BLOCKS = 512;
constexpr int NODE_WAVES  = NODE_BLOCKS * 4;

static __device__ __forceinline__ unsigned pack_bf16(float a, float b) {
    __hip_bfloat162 h = __float22bfloat162_rn(float2{a, b});
    return *reinterpret_cast<unsigned*>(&h);
}
static __device__ __forceinline__ float bf16r(float v) {
    __hip_bfloat16 h = __float2bfloat16(v);
    return __bfloat162float(h);
}

// ---------------------------------------------------------------------------
// Fill: sentinel-init padded bucket, zero cnt, zero xb row NN.
// ---------------------------------------------------------------------------
__global__ __launch_bounds__(256) void k_fill(int2* __restrict__ bucket,
                                              int* __restrict__ cnt,
                                              unsigned* __restrict__ xb32) {
    const int i = blockIdx.x * 256 + threadIdx.x;
    if (i < SLOTS_MAX) bucket[i] = make_int2(NN, 0);  // pad: zero x-row, ea[0]
    if (i < NN) cnt[i] = 0;
    if (i < 32) xb32[NN * 32 + i] = 0;                // zero row NN of xb
}

// ---------------------------------------------------------------------------
// x (f32) -> x_bf16 table (50000 x 64)
// ---------------------------------------------------------------------------
__global__ __launch_bounds__(256) void k_xcvt(const float* __restrict__ x,
                                              unsigned* __restrict__ xb32) {
    const int i = blockIdx.x * 256 + threadIdx.x;  // per 8 elements
    if (i >= NN * FN / 8) return;
    const float4* p = (const float4*)(x + (size_t)i * 8);
    float4 f0 = p[0], f1 = p[1];
    uint4 o;
    o.x = pack_bf16(f0.x, f0.y);
    o.y = pack_bf16(f0.z, f0.w);
    o.z = pack_bf16(f1.x, f1.y);
    o.w = pack_bf16(f1.z, f1.w);
    ((uint4*)xb32)[i] = o;
}

// ---------------------------------------------------------------------------
// Precompute: uW2b[g][j] = b2[j] + u[g]·W2_u[:,j]  (blocks 0..63, exact f32)
//             corr[j] = relu(bf16(ea[0])·bf16(W1_bot[:,j]) + b1[j]) (block 64)
// corr matches the MFMA pad-message to ~1e-6 (bf16 products exact in f32).
// ---------------------------------------------------------------------------
__global__ __launch_bounds__(256) void k_pre(const float* __restrict__ u,
                                             const float* __restrict__ W2,
                                             const float* __restrict__ b2,
                                             const float* __restrict__ ea,
                                             const float* __restrict__ W1,
                                             const float* __restrict__ b1,
                                             float* __restrict__ uW2b,
                                             float* __restrict__ corr) {
    if (blockIdx.x == NG / 4) {  // corr block
        const int j = threadIdx.x;
        if (j < OD) {
            float acc = b1[j];
#pragma unroll
            for (int k = 0; k < FE; ++k) {
                const float ek = bf16r(ea[k]);
                const float wk = bf16r(W1[(FN + k) * OD + j]);
                acc = fmaf(ek, wk, acc);
            }
            corr[j] = fmaxf(acc, 0.0f);
        }
        return;
    }
    const int lane = threadIdx.x & 63;
    float wcol[FG];
#pragma unroll
    for (int k = 0; k < FG; ++k) wcol[k] = W2[(FN + OD + k) * OD + lane];
    const float bias = b2[lane];

    int g = (blockIdx.x * blockDim.x + threadIdx.x) >> 6;
    g = __builtin_amdgcn_readfirstlane(g);
    if (g >= NG) return;

    const float* __restrict__ urow = u + (size_t)g * FG;
    float acc = bias;
#pragma unroll
    for (int k = 0; k < FG; ++k) acc = fmaf(urow[k], wcol[k], acc);
    uW2b[(size_t)g * OD + lane] = acc;
}

// ---------------------------------------------------------------------------
// Bucketing: histogram, scan over PADDED counts (ceil16), scatter.
// ---------------------------------------------------------------------------
__global__ __launch_bounds__(256) void k_hist(const int* __restrict__ ei,
                                              int* __restrict__ cnt) {
    const int e = blockIdx.x * blockDim.x + threadIdx.x;
    if (e < NE) atomicAdd(&cnt[ei[e]], 1);
}

__global__ __launch_bounds__(SCAN_B) void k_scan1(const int* __restrict__ cnt,
                                                  int* __restrict__ pstart,
                                                  int* __restrict__ bsum) {
    __shared__ int lds[SCAN_B];
    const int i = blockIdx.x * SCAN_B + threadIdx.x;
    const int v = (i < NN) ? (((cnt[i] + 15) >> 4) << 4) : 0;  // padded count
    lds[threadIdx.x] = v;
    __syncthreads();
#pragma unroll
    for (int off = 1; off < SCAN_B; off <<= 1) {
        int t = (threadIdx.x >= off) ? lds[threadIdx.x - off] : 0;
        __syncthreads();
        lds[threadIdx.x] += t;
        __syncthreads();
    }
    const int incl = lds[threadIdx.x];
    if (i < NN) pstart[i] = incl - v;  // exclusive within block
    if (threadIdx.x == SCAN_B - 1) bsum[blockIdx.x] = incl;
}

__global__ __launch_bounds__(SCAN_B) void k_scan2(const int* __restrict__ bsum,
                                                  int* __restrict__ bscan) {
    __shared__ int lds[SCAN_B];
    const int i = threadIdx.x;
    const int v = (i < NBLK) ? bsum[i] : 0;
    lds[i] = v;
    __syncthreads();
#pragma unroll
    for (int off = 1; off < SCAN_B; off <<= 1) {
        int t = (i >= off) ? lds[i - off] : 0;
        __syncthreads();
        lds[i] += t;
        __syncthreads();
    }
    if (i < NBLK) bscan[i] = lds[i] - v;
}

__global__ __launch_bounds__(SCAN_B) void k_scan3(int* __restrict__ pstart,
                                                  const int* __restrict__ bscan,
                                                  const int* __restrict__ cnt,
                                                  int* __restrict__ cursor) {
    const int i = blockIdx.x * SCAN_B + threadIdx.x;
    if (i < NN) {
        const int s = pstart[i] + bscan[blockIdx.x];
        pstart[i] = s;
        cursor[i] = s;
        if (i == NN - 1) pstart[NN] = s + (((cnt[i] + 15) >> 4) << 4);
    }
}

__global__ __launch_bounds__(256) void k_scatter(const int* __restrict__ ei,
                                                 int* __restrict__ cursor,
                                                 int2* __restrict__ bucket) {
    const int e = blockIdx.x * blockDim.x + threadIdx.x;
    if (e < NE) {
        const int dst = ei[e];
        const int src = ei[NE + e];
        const int pos = atomicAdd(&cursor[dst], 1);
        bucket[pos] = make_int2(src, e);
    }
}

// ---------------------------------------------------------------------------
// Window-parallel MFMA: window w = bucket[16w..16w+15] (uniform, padded).
//   partial[w][j] = sum_r relu( [x_bf16[src_r] | ea_r] @ W1 + b1 )[j]
// All iterations independent -> deep pipelining; bucket loads coalesced.
// Fragment layouts (mfma_f32_16x16x32_bf16):
//   A: row = lane&15, k = 8*(lane>>4)+i ; B: col = lane&15, same k
//   C: col = lane&15, row = (lane>>4)*4 + q   [measured m89]
// ---------------------------------------------------------------------------
__global__ __launch_bounds__(256) void k_aggw(const int2* __restrict__ bucket,
                                              const float* __restrict__ ea,
                                              const unsigned short* __restrict__ xb,
                                              const float* __restrict__ W1,
                                              const float* __restrict__ b1,
                                              const int* __restrict__ pstart,
                                              float* __restrict__ partial) {
    const int l = threadIdx.x & 63;
    const int g = l >> 4;
    const int c = l & 15;

    // W1 B-fragments: wf[t][b] covers k = 32t.., cols 16b..16b+15
    short8 wf[3][4];
#pragma unroll
    for (int t = 0; t < 3; ++t)
#pragma unroll
        for (int b = 0; b < 4; ++b)
#pragma unroll
            for (int i = 0; i < 8; i += 2) {
                const int k = 32 * t + 8 * g + i;
                const unsigned p = pack_bf16(W1[k * OD + (c + 16 * b)],
                                             W1[(k + 1) * OD + (c + 16 * b)]);
                ((unsigned*)&wf[t][b])[i / 2] = p;
            }
    float bias[4];
#pragma unroll
    for (int b = 0; b < 4; ++b) bias[b] = b1[c + 16 * b];

    const int nwin = pstart[NN] >> 4;  // uniform scalar load

    int wv = (blockIdx.x * blockDim.x + threadIdx.x) >> 6;
    wv = __builtin_amdgcn_readfirstlane(wv);

#pragma unroll 2
    for (int w = wv; w < nwin; w += AGG_WAVES) {
        const int2 se = bucket[(size_t)w * 16 + c];  // coalesced, broadcast over g

        // A fragments: chunks 0,1 = x_bf16[src], chunk 2 = cvt(ea[e])
        short8 a0, a1, a2;
        {
            const uint4* xr = (const uint4*)(xb + (size_t)se.x * FN);
            uint4 q0 = xr[g];
            uint4 q1 = xr[4 + g];
            a0 = *(short8*)&q0;
            a1 = *(short8*)&q1;
        }
        {
            const float4* er = (const float4*)(ea + (size_t)se.y * FE);
            float4 e0 = er[2 * g], e1 = er[2 * g + 1];
            uint4 q2;
            q2.x = pack_bf16(e0.x, e0.y);
            q2.y = pack_bf16(e0.z, e0.w);
            q2.z = pack_bf16(e1.x, e1.y);
            q2.w = pack_bf16(e1.z, e1.w);
            a2 = *(short8*)&q2;
        }

        float sv[4];
#pragma unroll
        for (int b = 0; b < 4; ++b) {
            f32x4 acc = {0.f, 0.f, 0.f, 0.f};
            acc = __builtin_amdgcn_mfma_f32_16x16x32_bf16(a0, wf[0][b], acc, 0, 0, 0);
            acc = __builtin_amdgcn_mfma_f32_16x16x32_bf16(a1, wf[1][b], acc, 0, 0, 0);
            acc = __builtin_amdgcn_mfma_f32_16x16x32_bf16(a2, wf[2][b], acc, 0, 0, 0);
            float s = fmaxf(acc[0] + bias[b], 0.0f) + fmaxf(acc[1] + bias[b], 0.0f)
                    + fmaxf(acc[2] + bias[b], 0.0f) + fmaxf(acc[3] + bias[b], 0.0f);
            s += __shfl_xor(s, 16);
            s += __shfl_xor(s, 32);
            sv[b] = s;
        }
        float v = sv[0];
        v = (g == 1) ? sv[1] : v;
        v = (g == 2) ? sv[2] : v;
        v = (g == 3) ? sv[3] : v;
        partial[(size_t)w * 64 + l] = v;  // l == c + 16g, coalesced
    }
}

// ---------------------------------------------------------------------------
// Reduce windows per node: aggb[n] = bf16( sum partials - pads*corr )
// ---------------------------------------------------------------------------
__global__ __launch_bounds__(256) void k_red(const float* __restrict__ partial,
                                             const int* __restrict__ pstart,
                                             const int* __restrict__ cnt,
                                             const float* __restrict__ corr,
                                             unsigned short* __restrict__ aggb) {
    const int l = threadIdx.x & 63;
    int n = (blockIdx.x * blockDim.x + threadIdx.x) >> 6;
    n = __builtin_amdgcn_readfirstlane(n);
    if (n >= NN) return;

    const int w0 = pstart[n] >> 4;
    const int w1 = pstart[n + 1] >> 4;
    float s = 0.0f;
    for (int w = w0; w < w1; ++w) s += partial[(size_t)w * 64 + l];
    const int pads = ((w1 - w0) << 4) - cnt[n];
    s -= (float)pads * corr[l];
    __hip_bfloat16 hb = __float2bfloat16(s);
    aggb[(size_t)n * OD + l] = *reinterpret_cast<unsigned short*>(&hb);
}

// ---------------------------------------------------------------------------
// Node MLP via MFMA: out = relu([x_bf16 | agg_bf16] @ W2[0:128] + uW2b[batch])
// ---------------------------------------------------------------------------
__global__ __launch_bounds__(256) void k_nodem(const unsigned short* __restrict__ xb,
                                               const unsigned short* __restrict__ aggb,
                                               const int* __restrict__ bat,
                                               const float* __restrict__ uW2b,
                                               const float* __restrict__ W2,
                                               float* __restrict__ out) {
    const int l = threadIdx.x & 63;
    const int g = l >> 4;
    const int c = l & 15;

    short8 wf[4][4];
#pragma unroll
    for (int t = 0; t < 4; ++t)
#pragma unroll
        for (int b = 0; b < 4; ++b)
#pragma unroll
            for (int i = 0; i < 8; i += 2) {
                const int k = 32 * t + 8 * g + i;
                const unsigned p = pack_bf16(W2[k * OD + (c + 16 * b)],
                                             W2[(k + 1) * OD + (c + 16 * b)]);
                ((unsigned*)&wf[t][b])[i / 2] = p;
            }

    int wv = (blockIdx.x * blockDim.x + threadIdx.x) >> 6;
    wv = __builtin_amdgcn_readfirstlane(wv);

    for (int w = wv; w < NWIN; w += NODE_WAVES) {
        const int n0 = w * 16;
        const uint4* xr = (const uint4*)(xb + (size_t)(n0 + c) * FN);
        const uint4* ar = (const uint4*)(aggb + (size_t)(n0 + c) * OD);
        uint4 qx0 = xr[g], qx1 = xr[4 + g];
        uint4 qa0 = ar[g], qa1 = ar[4 + g];
        short8 a0 = *(short8*)&qx0, a1 = *(short8*)&qx1;
        short8 a2 = *(short8*)&qa0, a3 = *(short8*)&qa1;

        int bq[4];
#pragma unroll
        for (int q = 0; q < 4; ++q) bq[q] = bat[n0 + g * 4 + q];

#pragma unroll
        for (int b = 0; b < 4; ++b) {
            f32x4 acc = {0.f, 0.f, 0.f, 0.f};
            acc = __builtin_amdgcn_mfma_f32_16x16x32_bf16(a0, wf[0][b], acc, 0, 0, 0);
            acc = __builtin_amdgcn_mfma_f32_16x16x32_bf16(a1, wf[1][b], acc, 0, 0, 0);
            acc = __builtin_amdgcn_mfma_f32_16x16x32_bf16(a2, wf[2][b], acc, 0, 0, 0);
            acc = __builtin_amdgcn_mfma_f32_16x16x32_bf16(a3, wf[3][b], acc, 0, 0, 0);
#pragma unroll
            for (int q = 0; q < 4; ++q) {
                const int n = n0 + g * 4 + q;
                const float val = acc[q] + uW2b[(size_t)bq[q] * OD + c + 16 * b];
                out[(size_t)n * OD + c + 16 * b] = fmaxf(val, 0.0f);
            }
        }
    }
}

// ---------------------------------------------------------------------------
extern "C" void kernel_launch(void* const* d_in, const int* in_sizes, int n_in,
                              void* d_out, int out_size, void* d_ws, size_t ws_size,
                              hipStream_t stream) {
    const float* x    = (const float*)d_in[0];   // (50000, 64)
    const int*   ei   = (const int*)d_in[1];     // (2, 800000)
    const float* ea   = (const float*)d_in[2];   // (800000, 32)
    const float* u    = (const float*)d_in[3];   // (256, 32)
    const int*   bat  = (const int*)d_in[4];     // (50000,)
    const float* W1   = (const float*)d_in[5];   // (96, 64)
    const float* b1   = (const float*)d_in[6];   // (64,)
    const float* W2   = (const float*)d_in[7];   // (160, 64)
    const float* b2   = (const float*)d_in[8];   // (64,)
    float* out = (float*)d_out;                  // (50000, 64)

    // workspace layout (~51 MB)
    char* ws = (char*)d_ws;
    auto alloc = [&](size_t bytes) {
        char* p = ws;
        ws += (bytes + 255) & ~size_t(255);
        return p;
    };
    unsigned short* xb   = (unsigned short*)alloc((size_t)(NN + 1) * FN * 2); // +zero row
    unsigned short* aggb = (unsigned short*)alloc((size_t)NN * OD * 2);
    float* uW2b    = (float*)alloc((size_t)NG * OD * sizeof(float));
    float* corr    = (float*)alloc((size_t)OD * sizeof(float));
    int*   cnt     = (int*)alloc((size_t)NN * sizeof(int));
    int*   pstart  = (int*)alloc((size_t)(NN + 1) * sizeof(int));
    int*   cursor  = (int*)alloc((size_t)NN * sizeof(int));
    int*   bsum    = (int*)alloc((size_t)NBLK * sizeof(int));
    int*   bscan   = (int*)alloc((size_t)NBLK * sizeof(int));
    int2*  bucket  = (int2*)alloc((size_t)SLOTS_MAX * sizeof(int2));          // 12.4 MB
    float* partial = (float*)alloc((size_t)(SLOTS_MAX / 16) * OD * sizeof(float)); // 24.8 MB

    // init (sentinel bucket, zero cnt, zero xb pad row)
    k_fill<<<dim3((SLOTS_MAX + 255) / 256), dim3(256), 0, stream>>>(bucket, cnt, (unsigned*)xb);

    // precomputes
    k_xcvt<<<dim3((NN * FN / 8 + 255) / 256), dim3(256), 0, stream>>>(x, (unsigned*)xb);
    k_pre<<<dim3(NG / 4 + 1), dim3(256), 0, stream>>>(u, W2, b2, ea, W1, b1, uW2b, corr);

    // bucket edges by destination (padded offsets)
    k_hist<<<dim3((NE + 255) / 256), dim3(256), 0, stream>>>(ei, cnt);
    k_scan1<<<dim3(NBLK), dim3(SCAN_B), 0, stream>>>(cnt, pstart, bsum);
    k_scan2<<<dim3(1), dim3(SCAN_B), 0, stream>>>(bsum, bscan);
    k_scan3<<<dim3(NBLK), dim3(SCAN_B), 0, stream>>>(pstart, bscan, cnt, cursor);
    k_scatter<<<dim3((NE + 255) / 256), dim3(256), 0, stream>>>(ei, cursor, bucket);

    // window-parallel MFMA + per-node reduce
    k_aggw<<<dim3(AGG_BLOCKS), dim3(256), 0, stream>>>(bucket, ea, xb, W1, b1, pstart, partial);
    k_red<<<dim3((NN * 64 + 255) / 256), dim3(256), 0, stream>>>(partial, pstart, cnt, corr, aggb);

    // node MLP (MFMA)
    k_nodem<<<dim3(NODE_BLOCKS), dim3(256), 0, stream>>>(xb, aggb, bat, uW2b, W2, out);
}